// Round 5
// baseline (195.683 us; speedup 1.0000x reference)
//
#include <hip/hip_runtime.h>

// SpearmanCorrelationLoss on MI355X (gfx950) — R5
//
// Math: double-argsort ranks are a permutation of 1..N per column, so
// mean/var of ranks are exact constants; only S = Sum(rank_p*rank_t) needed:
//   corr_c = (S/N - 8192.5^2) / ((N^2-1)/12 + 2*EPS),  out = -mean_c(corr_c)
//
// Histogram ranking (ranks invariant under monotone maps): bucket =
// floor(sigmoid(1.702*x)*8192) ~ Gaussian CDF -> near-uniform buckets
// (lambda ~2.15). rank(x) = P[b(x)] + #{y in same bucket : y < x}
// (strict-less = lower_bound tie semantics; error ~1e-10 on output).
//
// R5 vs R4 (72.5 us main kernel, conflicts 1.34e7, 20+10 barrier scans):
//  - NBINS 4096->8192 via u16-PACKED cursors (2 bins/u32, counts<=16384 so
//    halves never carry into each other). LDS stays 80 KB -> 2 blocks/CU.
//    Divergent slice-scan wave-max drops ~11 -> ~7 iterations.
//  - wave-shuffle prefix sum: 20 barriers -> 4 per phase.
//  - wave-shuffle u64 final reduction: 10 barriers -> 2.

#define N_ROWS 16384
#define N_COLS 512
#define NT 1024
#define PT 16            // elements per thread
#define NBINS 8192
#define NWORDS (NBINS / 2)   // packed u16 cursor words

__device__ __forceinline__ unsigned f2key(float x) {
    // order-preserving fp32 -> u32 (no NaNs in input)
    unsigned u = __float_as_uint(x);
    return (u & 0x80000000u) ? ~u : (u | 0x80000000u);
}

// monotone approx Gaussian-CDF bucket: sigma(1.702x) = 1/(1+2^(-2.4554x))
__device__ __forceinline__ int f2bucket(float f) {
    float e = __builtin_amdgcn_exp2f(-2.4554f * f);   // v_exp_f32
    float s = __builtin_amdgcn_rcpf(1.0f + e);        // v_rcp_f32
    int b = (int)(s * (float)NBINS);
    return b < 0 ? 0 : (b > NBINS - 1 ? NBINS - 1 : b);
}

template <int TRANSPOSED>
__global__ __launch_bounds__(NT, 8)
void spearman_col_kernel(const float* __restrict__ A, const float* __restrict__ B,
                         double* __restrict__ col_corr) {
    __shared__ unsigned cursor[NWORDS];                  // 16 KB (u16-packed)
    __shared__ __align__(16) unsigned keys_sh[N_ROWS];   // 64 KB
    __shared__ unsigned wtot[16];
    __shared__ unsigned long long wred[16];
    const int col = blockIdx.x;
    const int tid = threadIdx.x;
    const int lane = tid & 63;
    const int wv = tid >> 6;

    unsigned rp2[PT / 2];          // packed u16 pred ranks (0-based, <16384)
    unsigned long long acc = 0;

    for (int phase = 0; phase < 2; ++phase) {
        const float* src = (phase == 0) ? A : B;

        // ---- load 16 elements; compute keys + buckets in registers ----
        unsigned key[PT];
        unsigned bkt2[PT / 2];     // packed u16 buckets
        if (TRANSPOSED) {
            const float4* colp = (const float4*)(src + (size_t)col * N_ROWS);
            #pragma unroll
            for (int m = 0; m < 4; ++m) {
                float4 f = colp[tid + m * NT];   // 16B/lane, coalesced
                key[4*m+0] = f2key(f.x); key[4*m+1] = f2key(f.y);
                key[4*m+2] = f2key(f.z); key[4*m+3] = f2key(f.w);
                bkt2[2*m+0] = (unsigned)f2bucket(f.x) | ((unsigned)f2bucket(f.y) << 16);
                bkt2[2*m+1] = (unsigned)f2bucket(f.z) | ((unsigned)f2bucket(f.w) << 16);
            }
        } else {
            #pragma unroll
            for (int s = 0; s < PT; s += 2) {
                float f0 = src[(size_t)(tid + (s+0) * NT) * N_COLS + col];
                float f1 = src[(size_t)(tid + (s+1) * NT) * N_COLS + col];
                key[s]   = f2key(f0);
                key[s+1] = f2key(f1);
                bkt2[s/2] = (unsigned)f2bucket(f0) | ((unsigned)f2bucket(f1) << 16);
            }
        }

        // ---- zero packed histogram ----
        __syncthreads();   // previous phase's keys_sh/cursor readers done
        ((uint4*)cursor)[tid] = make_uint4(0u, 0u, 0u, 0u);
        __syncthreads();

        // ---- histogram: +1 into the u16 half of word b>>1 ----
        #pragma unroll
        for (int s = 0; s < PT; ++s) {
            unsigned b = (bkt2[s/2] >> ((s & 1) * 16)) & 0xFFFFu;
            atomicAdd(&cursor[b >> 1], 1u << ((b & 1) * 16));
        }
        __syncthreads();

        // ---- exclusive prefix over 8192 u16 bins, wave-shuffle scan ----
        {
            uint4 h = ((uint4*)cursor)[tid];     // 4 words = 8 bins
            unsigned c0 = (h.x & 0xFFFFu), c1 = (h.x >> 16);
            unsigned c2 = (h.y & 0xFFFFu), c3 = (h.y >> 16);
            unsigned c4 = (h.z & 0xFFFFu), c5 = (h.z >> 16);
            unsigned c6 = (h.w & 0xFFFFu), c7 = (h.w >> 16);
            unsigned mysum = c0 + c1 + c2 + c3 + c4 + c5 + c6 + c7;
            unsigned incl = mysum;
            #pragma unroll
            for (int off = 1; off < 64; off <<= 1) {
                unsigned v = __shfl_up(incl, off, 64);
                if (lane >= off) incl += v;
            }
            if (lane == 63) wtot[wv] = incl;
            __syncthreads();
            if (tid < 16) {
                unsigned v = wtot[tid];
                unsigned in2 = v;
                #pragma unroll
                for (int off = 1; off < 16; off <<= 1) {
                    unsigned q = __shfl_up(in2, off, 64);
                    if (tid >= off) in2 += q;
                }
                wtot[tid] = in2;
            }
            __syncthreads();
            unsigned r = ((wv == 0) ? 0u : wtot[wv - 1]) + incl - mysum;
            uint4 o;
            o.x = r | ((r + c0) << 16); r += c0 + c1;
            o.y = r | ((r + c2) << 16); r += c2 + c3;
            o.z = r | ((r + c4) << 16); r += c4 + c5;
            o.w = r | ((r + c6) << 16); r += c6 + c7;
            ((uint4*)cursor)[tid] = o;
        }
        __syncthreads();

        // ---- scatter keys into bucket slices (packed-half atomicAdd) ----
        #pragma unroll
        for (int s = 0; s < PT; ++s) {
            unsigned b = (bkt2[s/2] >> ((s & 1) * 16)) & 0xFFFFu;
            unsigned old = atomicAdd(&cursor[b >> 1], 1u << ((b & 1) * 16));
            unsigned slot = (old >> ((b & 1) * 16)) & 0xFFFFu;
            keys_sh[slot] = key[s];
        }
        __syncthreads();   // after this: half b of cursor == P[b+1]

        // ---- rank: P[b] + strict-less count within slice ----
        const unsigned short* cur16 = (const unsigned short*)cursor;
        #pragma unroll
        for (int s = 0; s < PT; ++s) {
            unsigned b = (bkt2[s/2] >> ((s & 1) * 16)) & 0xFFFFu;
            unsigned k = key[s];
            unsigned lo = (b == 0) ? 0u : (unsigned)cur16[b - 1];
            unsigned hi = (unsigned)cur16[b];
            unsigned r = lo;                       // P[b]
            for (unsigned j = lo; j < hi; ++j)
                r += (keys_sh[j] < k) ? 1u : 0u;
            if (phase == 0) {
                if ((s & 1) == 0) rp2[s/2] = r;
                else              rp2[s/2] |= (r << 16);
            } else {
                unsigned rp = (rp2[s/2] >> ((s & 1) * 16)) & 0xFFFFu;
                acc += (unsigned long long)(rp + 1) * (unsigned long long)(r + 1);
            }
        }
    }

    // ---- exact u64 reduction: wave shuffle + cross-wave ----
    #pragma unroll
    for (int off = 32; off > 0; off >>= 1)
        acc += __shfl_down(acc, off, 64);
    if (lane == 0) wred[wv] = acc;
    __syncthreads();
    if (tid == 0) {
        unsigned long long S = 0;
        #pragma unroll
        for (int w = 0; w < 16; ++w) S += wred[w];
        double Sd = (double)S;                          // exact (< 2^53)
        double cov = Sd / (double)N_ROWS - 67117056.25; // 8192.5^2
        double denom = 22369621.25 + 2e-6;              // (N^2-1)/12 + 2*EPS
        col_corr[col] = cov / denom;
    }
}

// 64x64 tile transpose: in [16384,512] row-major -> out [512,16384]
__global__ __launch_bounds__(256)
void transpose_kernel(const float* __restrict__ in0, const float* __restrict__ in1,
                      float* __restrict__ out0, float* __restrict__ out1) {
    __shared__ float tile[64][65];
    const float* in  = blockIdx.z ? in1 : in0;
    float* out       = blockIdx.z ? out1 : out0;
    const int r0 = blockIdx.x * 64;
    const int c0 = blockIdx.y * 64;
    const int t = threadIdx.x;
    const int cg = (t & 15) * 4;
    const int rr = t >> 4;
    #pragma unroll
    for (int it = 0; it < 4; ++it) {
        int r = rr + it * 16;
        float4 f = *(const float4*)&in[(size_t)(r0 + r) * N_COLS + c0 + cg];
        tile[r][cg + 0] = f.x; tile[r][cg + 1] = f.y;
        tile[r][cg + 2] = f.z; tile[r][cg + 3] = f.w;
    }
    __syncthreads();
    const int rg = (t & 15) * 4;
    const int cc = t >> 4;
    #pragma unroll
    for (int it = 0; it < 4; ++it) {
        int c = cc + it * 16;
        float4 f;
        f.x = tile[rg + 0][c]; f.y = tile[rg + 1][c];
        f.z = tile[rg + 2][c]; f.w = tile[rg + 3][c];
        *(float4*)&out[(size_t)(c0 + c) * N_ROWS + r0 + rg] = f;
    }
}

__global__ void finalize_kernel(const double* __restrict__ col_corr,
                                float* __restrict__ out) {
    __shared__ double red[N_COLS];
    int t = threadIdx.x;
    red[t] = col_corr[t];
    __syncthreads();
    for (int off = N_COLS / 2; off > 0; off >>= 1) {
        if (t < off) red[t] += red[t + off];
        __syncthreads();
    }
    if (t == 0) out[0] = (float)(-red[0] / (double)N_COLS);
}

extern "C" void kernel_launch(void* const* d_in, const int* in_sizes, int n_in,
                              void* d_out, int out_size, void* d_ws, size_t ws_size,
                              hipStream_t stream) {
    const float* pred   = (const float*)d_in[0];
    const float* target = (const float*)d_in[1];
    float* out = (float*)d_out;

    const size_t mat_bytes = (size_t)N_ROWS * N_COLS * sizeof(float);
    double* col_corr = (double*)d_ws;                       // 4 KB
    float* predT   = (float*)((char*)d_ws + 65536);
    float* targetT = predT + (size_t)N_ROWS * N_COLS;
    const size_t need = 65536 + 2 * mat_bytes;

    if (ws_size >= need) {
        dim3 tgrid(N_ROWS / 64, N_COLS / 64, 2);
        transpose_kernel<<<tgrid, 256, 0, stream>>>(pred, target, predT, targetT);
        spearman_col_kernel<1><<<N_COLS, NT, 0, stream>>>(predT, targetT, col_corr);
    } else {
        spearman_col_kernel<0><<<N_COLS, NT, 0, stream>>>(pred, target, col_corr);
    }
    finalize_kernel<<<1, N_COLS, 0, stream>>>(col_corr, out);
}